// Round 3
// baseline (1093.506 us; speedup 1.0000x reference)
//
#include <hip/hip_runtime.h>
#include <stdint.h>

#define TT 4096
#define HID 7168
#define QL 1536
#define NH 64
#define HD 128
#define QD 8192
#define KTOP 2048
#define WSCALE 0.011048543456039806f

typedef _Float16 f16;
typedef uint16_t u16;
typedef unsigned u32;
typedef __attribute__((ext_vector_type(4))) float f32x4;
typedef __attribute__((ext_vector_type(16))) float f32x16;
typedef __attribute__((ext_vector_type(8))) _Float16 f16x8;
typedef __attribute__((ext_vector_type(4))) _Float16 f16x4;

__device__ __forceinline__ void lds_load16(const void* g, void* l) {
  __builtin_amdgcn_global_load_lds(
      (const __attribute__((address_space(1))) unsigned*)g,
      (__attribute__((address_space(3))) unsigned*)l, 16, 0, 0);
}

__device__ __forceinline__ u16 f16_bits(f16 h) {
  union { f16 h; u16 u; } c; c.h = h; return c.u;
}
__device__ __forceinline__ float f16_from_bits(u16 u) {
  union { u16 u; f16 h; } c; c.u = u; return (float)c.h;
}

// ---------------- tiled transpose f32[R][C] -> f16 out[(c+orow0)][r] ----------------
__global__ void tcvt(const float* __restrict__ in, f16* __restrict__ out,
                     int R, int C, int ostride, int orow0) {
  __shared__ float tile[32][33];
  int cb = blockIdx.x * 32, rb = blockIdx.y * 32;
  int tx = threadIdx.x & 31, ty = threadIdx.x >> 5;  // ty 0..7
  for (int i = 0; i < 32; i += 8)
    tile[ty + i][tx] = in[(size_t)(rb + ty + i) * C + cb + tx];
  __syncthreads();
  for (int i = 0; i < 32; i += 8)
    out[(size_t)(cb + ty + i + orow0) * ostride + rb + tx] = (f16)tile[tx][ty + i];
}

// ---------------- q16 = f16(qr @ Wq_b)  (A fp32 via ds_write staging, B f16; 128x128, BK=32) ----------------
__launch_bounds__(256, 2)
__global__ void gemm_q(const float* __restrict__ A, const f16* __restrict__ B, f16* __restrict__ C) {
  __shared__ __align__(16) f16 As[128 * 32];
  __shared__ __align__(16) f16 Bs[128 * 32];
  int tid = threadIdx.x, lane = tid & 63, wave = tid >> 6;
  int bm = blockIdx.y << 7, bn = blockIdx.x << 7;
  int wm = (wave & 1) << 6, wn = (wave >> 1) << 6;
  const f16* gb = B + (size_t)(bn + (tid >> 2)) * QL + (tid & 3) * 8;
  f16* lB = Bs + wave * 512;
  int ar = tid >> 3, ac = (tid & 7) * 4;
  f32x4 acc[4][4] = {};
  for (int k0 = 0; k0 < QL; k0 += 32) {
    __syncthreads();
#pragma unroll
    for (int i = 0; i < 4; i++) {
      float4 v = *(const float4*)(A + (size_t)(bm + ar + i * 32) * QL + k0 + ac);
      f16x4 h = {(f16)v.x, (f16)v.y, (f16)v.z, (f16)v.w};
      *(f16x4*)(As + (ar + i * 32) * 32 + ac) = h;
    }
    lds_load16(gb + k0, lB);
    lds_load16(gb + (size_t)64 * QL + k0, lB + 2048);
    __syncthreads();
    int ro = lane & 15, ko = (lane >> 4) << 3;
    f16x8 af[4], bf[4];
#pragma unroll
    for (int i = 0; i < 4; i++) af[i] = *(const f16x8*)(As + (wm + i * 16 + ro) * 32 + ko);
#pragma unroll
    for (int i = 0; i < 4; i++) bf[i] = *(const f16x8*)(Bs + (wn + i * 16 + ro) * 32 + ko);
#pragma unroll
    for (int mi = 0; mi < 4; mi++)
#pragma unroll
      for (int ni = 0; ni < 4; ni++)
        acc[mi][ni] = __builtin_amdgcn_mfma_f32_16x16x32_f16(af[mi], bf[ni], acc[mi][ni], 0, 0, 0);
  }
  int cr = (lane >> 4) << 2, cc = lane & 15;
#pragma unroll
  for (int mi = 0; mi < 4; mi++)
#pragma unroll
    for (int ni = 0; ni < 4; ni++) {
      int row = bm + wm + mi * 16 + cr;
      int col = bn + wn + ni * 16 + cc;
      f16* cp = C + (size_t)row * QD + col;
#pragma unroll
      for (int r = 0; r < 4; r++) cp[(size_t)r * QD] = (f16)acc[mi][ni][r];
    }
}

// ---------------- [kraw | w] = hs @ [Wk | Wproj]  (A fp32 via ds_write staging; 64x64, BK=64) ----------------
__launch_bounds__(256, 2)
__global__ void gemm_kw(const float* __restrict__ A, const f16* __restrict__ B,
                        float* __restrict__ kraw, float* __restrict__ wout) {
  __shared__ __align__(16) f16 As[64 * 64];
  __shared__ __align__(16) f16 Bs[64 * 64];
  int tid = threadIdx.x, lane = tid & 63, wave = tid >> 6;
  int bm = blockIdx.y << 6, bn = blockIdx.x << 6;
  int wm = (wave & 1) << 5, wn = (wave >> 1) << 5;
  const f16* gb = B + (size_t)(bn + (tid >> 3)) * HID + (tid & 7) * 8;
  f16* lB = Bs + wave * 512;
  int ar = tid >> 4, ac = (tid & 15) * 4;
  f32x4 acc[2][2] = {};
  for (int k0 = 0; k0 < HID; k0 += 64) {
    __syncthreads();
#pragma unroll
    for (int i = 0; i < 4; i++) {
      float4 v = *(const float4*)(A + (size_t)(bm + ar + i * 16) * HID + k0 + ac);
      f16x4 h = {(f16)v.x, (f16)v.y, (f16)v.z, (f16)v.w};
      *(f16x4*)(As + (ar + i * 16) * 64 + ac) = h;
    }
    lds_load16(gb + k0, lB);
    lds_load16(gb + (size_t)32 * HID + k0, lB + 2048);
    __syncthreads();
    int ro = lane & 15, ko = (lane >> 4) << 3;
    f16x8 af[2][2], bf[2][2];
#pragma unroll
    for (int i = 0; i < 2; i++)
#pragma unroll
      for (int kk = 0; kk < 2; kk++) {
        af[i][kk] = *(const f16x8*)(As + (wm + i * 16 + ro) * 64 + kk * 32 + ko);
        bf[i][kk] = *(const f16x8*)(Bs + (wn + i * 16 + ro) * 64 + kk * 32 + ko);
      }
#pragma unroll
    for (int mi = 0; mi < 2; mi++)
#pragma unroll
      for (int ni = 0; ni < 2; ni++)
#pragma unroll
        for (int kk = 0; kk < 2; kk++)
          acc[mi][ni] = __builtin_amdgcn_mfma_f32_16x16x32_f16(af[mi][kk], bf[ni][kk], acc[mi][ni], 0, 0, 0);
  }
  int cr = (lane >> 4) << 2, cc = lane & 15;
#pragma unroll
  for (int mi = 0; mi < 2; mi++)
#pragma unroll
    for (int ni = 0; ni < 2; ni++) {
      int row = bm + wm + mi * 16 + cr;
      int col = bn + wn + ni * 16 + cc;
#pragma unroll
      for (int r = 0; r < 4; r++) {
        float v = acc[mi][ni][r];
        int rr = row + r;
        if (col < HD) kraw[(size_t)rr * HD + col] = v;
        else          wout[(size_t)rr * NH + (col - HD)] = v * WSCALE;
      }
    }
}

// ---------------- layernorm + rope on k -> f16 ----------------
__global__ void ln_rope(const float* __restrict__ kraw, const int* __restrict__ pos,
                        const float* __restrict__ gamma, const float* __restrict__ beta,
                        f16* __restrict__ k16) {
  int row = (blockIdx.x << 2) + (threadIdx.x >> 6);
  int lane = threadIdx.x & 63;
  const float* kr = kraw + (size_t)row * HD;
  float2 x = ((const float2*)kr)[lane];
  float s = x.x + x.y, s2 = x.x * x.x + x.y * x.y;
  for (int off = 32; off; off >>= 1) { s += __shfl_down(s, off); s2 += __shfl_down(s2, off); }
  s = __shfl(s, 0); s2 = __shfl(s2, 0);
  float mu = s * (1.f / 128.f);
  float var = s2 * (1.f / 128.f) - mu * mu;
  float inv = rsqrtf(var + 1e-6f);
  float y0 = (x.x - mu) * inv * gamma[lane * 2] + beta[lane * 2];
  float y1 = (x.y - mu) * inv * gamma[lane * 2 + 1] + beta[lane * 2 + 1];
  float o0 = y0, o1 = y1;
  if (lane < 32) {
    float p = (float)pos[row];
    float invf = exp2f(-(float)lane * 0.41524101185942813f);  // 10000^(-2l/64)
    float ang = p * invf;
    float sn, cn;
    sincosf(ang, &sn, &cn);
    o0 = y0 * cn - y1 * sn;
    o1 = y0 * sn + y1 * cn;
  }
  k16[(size_t)row * HD + 2 * lane] = (f16)o0;
  k16[(size_t)row * HD + 2 * lane + 1] = (f16)o1;
}

// ---------------- per-row: rope(q), f16 MFMA scores (Q in regs), bitonic top-k, fp32 out ----------------
__launch_bounds__(256, 3)
__global__ void scores_topk(const f16* __restrict__ q16, const f16* __restrict__ k16,
                            const float* __restrict__ w, const int* __restrict__ pos,
                            float* __restrict__ out) {
  int t = blockIdx.x;
  int tid = threadIdx.x, lane = tid & 63, wave = tid >> 6;
  __shared__ __align__(16) unsigned char smem[49408];
  f16* ks = (f16*)smem;                 // 32KB: K tile, units [kg(16)][s(128)] x 8 f16
  f16* qk = (f16*)(smem + 32768);       // 16KB: q row units [kg(16)][h(64)] x 8 f16; later keys
  u32* key = (u32*)(smem + 32768);      // aliases qk (4096 keys)
  float* css = (float*)(smem + 49152);  // 64 floats: cos[32] sin[32]

  // stage q row (contiguous global, permuted into [kg][h] units); build cos/sin
  {
    const f16* qrow = q16 + (size_t)t * QD;
#pragma unroll
    for (int j = 0; j < 4; j++) {
      int u = j * 256 + tid;
      int kg = u >> 6, h = u & 63;
      lds_load16(qrow + h * 128 + kg * 8, qk + (size_t)(j * 256 + wave * 64) * 8);
    }
    if (tid < 32) {
      float invf = exp2f(-(float)tid * 0.41524101185942813f);
      float ang = (float)pos[t] * invf;
      float sn, cn;
      sincosf(ang, &sn, &cn);
      css[tid] = cn;
      css[32 + tid] = sn;
    }
  }
  __syncthreads();
  // rope q in LDS: 64 heads x 32 pairs (dims 0..63)
#pragma unroll
  for (int i = 0; i < 8; i++) {
    int p = tid + (i << 8);
    int h = p >> 5, l = p & 31;
    int d = l * 2;
    int base = ((d >> 3) * 64 + h) * 8 + (d & 7);
    float q0 = (float)qk[base], q1 = (float)qk[base + 1];
    float cn = css[l], sn = css[32 + l];
    qk[base] = (f16)(q0 * cn - q1 * sn);
    qk[base + 1] = (f16)(q0 * sn + q1 * cn);
  }
  __syncthreads();
  // Q into registers: A-frags for 32x32x16 (m=lane&31, k=(lane>>5)*8+j)
  f16x8 afr[2][8];
  {
    int m = lane & 31;
#pragma unroll
    for (int mi = 0; mi < 2; mi++)
#pragma unroll
      for (int kk = 0; kk < 8; kk++) {
        int kg = kk * 2 + (lane >> 5);
        afr[mi][kk] = *(const f16x8*)(qk + (size_t)(kg * 64 + mi * 32 + m) * 8);
      }
  }
  // per-lane head weights (C-layout rows this lane owns)
  float wreg[32];
  {
    int hf = lane >> 5;
    const float* wr = w + (size_t)t * 64;
#pragma unroll
    for (int mi = 0; mi < 2; mi++)
#pragma unroll
      for (int r = 0; r < 16; r++)
        wreg[mi * 16 + r] = wr[mi * 32 + (r & 3) + ((r >> 2) << 3) + (hf << 2)];
  }
  __syncthreads();  // q reads done -> qk region becomes key[]

  int nsort = (t <= 2047) ? 2048 : 4096;
  for (int s = tid; s < nsort; s += 256)
    key[s] = 0xFFFFu - (u32)s;   // fill: mono16 = 0 sorts below all reals

  int ntile = (t >> 7) + 1;
  int sw = wave << 5;
  for (int st = 0; st < ntile; st++) {
    int s0 = st << 7;
    __syncthreads();
    {
      const f16* kb = k16 + (size_t)s0 * HD;
#pragma unroll
      for (int j = 0; j < 8; j++) {
        int u = j * 256 + tid;
        int kg = u >> 7, s = u & 127;
        lds_load16(kb + s * HD + kg * 8, ks + (size_t)(j * 256 + wave * 64) * 8);
      }
    }
    __syncthreads();
    f32x16 acc0 = {}, acc1 = {};
    int nlo = lane & 31;
#pragma unroll
    for (int kk = 0; kk < 8; kk++) {
      int kg = kk * 2 + (lane >> 5);
      f16x8 bfr = *(const f16x8*)(ks + (size_t)(kg * 128 + sw + nlo) * 8);
      acc0 = __builtin_amdgcn_mfma_f32_32x32x16_f16(afr[0][kk], bfr, acc0, 0, 0, 0);
      acc1 = __builtin_amdgcn_mfma_f32_32x32x16_f16(afr[1][kk], bfr, acc1, 0, 0, 0);
    }
    float partial = 0.f;
#pragma unroll
    for (int r = 0; r < 16; r++) {
      partial += wreg[r] * fmaxf(acc0[r], 0.f);
      partial += wreg[16 + r] * fmaxf(acc1[r], 0.f);
    }
    partial += __shfl_xor(partial, 32);
    int s = s0 + sw + nlo;
    if (lane < 32 && s <= t) {
      if (!(partial == partial)) partial = 0.f;                 // NaN scrub
      partial = fminf(fmaxf(partial, -60000.f), 60000.f);       // keep f16-finite
      u16 hb = f16_bits((f16)partial);
      u32 m = (hb & 0x8000u) ? (u32)(hb ^ 0xFFFFu) : (u32)(hb | 0x8000u);
      key[s] = (m << 16) | (0xFFFFu - (u32)s);
    }
  }

  // bitonic sort descending (val desc, idx asc via packed key)
  for (int kk = 2; kk <= nsort; kk <<= 1)
    for (int j = kk >> 1; j > 0; j >>= 1) {
      __syncthreads();
      int half = nsort >> 1;
      for (int m = tid; m < half; m += 256) {
        int i = ((m & ~(j - 1)) << 1) | (m & (j - 1));
        int l = i | j;
        u32 a = key[i], b = key[l];
        bool up = ((i & kk) == 0);
        if (up ? (a < b) : (a > b)) { key[i] = b; key[l] = a; }
      }
    }
  __syncthreads();
  // fp32 stores: vals then idx (output dtype is float32!)
  for (int r = tid; r < KTOP; r += 256) {
    u32 kv = key[r];
    u32 m = kv >> 16;
    float v;
    if (m == 0u) {
      v = -1e30f;
    } else {
      u16 hb = (u16)((m & 0x8000u) ? (m ^ 0x8000u) : (m ^ 0xFFFFu));
      v = f16_from_bits(hb);
    }
    out[(size_t)t * KTOP + r] = v;
    out[(size_t)TT * KTOP + (size_t)t * KTOP + r] = (float)(0xFFFFu - (kv & 0xFFFFu));
  }
}

extern "C" void kernel_launch(void* const* d_in, const int* in_sizes, int n_in,
                              void* d_out, int out_size, void* d_ws, size_t ws_size,
                              hipStream_t stream) {
  const float* hs = (const float*)d_in[0];
  const float* qr = (const float*)d_in[1];
  const int* pos = (const int*)d_in[2];
  const float* Wq = (const float*)d_in[3];
  const float* Wk = (const float*)d_in[4];
  const float* Wp = (const float*)d_in[5];
  const float* gamma = (const float*)d_in[6];
  const float* beta = (const float*)d_in[7];
  char* ws = (char*)d_ws;
  // small buffers first, big streams last; total 99,221,504 B
  float* kraw = (float*)ws;                 //  2,097,152
  float* wsc = (float*)(ws + 2097152);      //  1,048,576
  f16* k16 = (f16*)(ws + 3145728);          //  1,048,576
  f16* kwT = (f16*)(ws + 4194304);          //  2,752,512  f16 [192][7168]
  f16* wqT = (f16*)(ws + 6946816);          // 25,165,824  f16 [8192][1536]
  f16* q16 = (f16*)(ws + 32112640);         // 67,108,864  f16 [4096][8192]

  tcvt<<<dim3(256, 48), dim3(256), 0, stream>>>(Wq, wqT, QL, QD, QL, 0);
  tcvt<<<dim3(4, 224), dim3(256), 0, stream>>>(Wk, kwT, HID, HD, HID, 0);
  tcvt<<<dim3(2, 224), dim3(256), 0, stream>>>(Wp, kwT, HID, NH, HID, HD);
  gemm_kw<<<dim3(3, 64), dim3(256), 0, stream>>>(hs, kwT, kraw, wsc);
  ln_rope<<<dim3(1024), dim3(256), 0, stream>>>(kraw, pos, gamma, beta, k16);
  gemm_q<<<dim3(64, 32), dim3(256), 0, stream>>>(qr, wqT, q16);
  scores_topk<<<dim3(4096), dim3(256), 0, stream>>>(q16, k16, wsc, pos, (float*)d_out);
}

// Round 4
// 851.596 us; speedup vs baseline: 1.2841x; 1.2841x over previous
//
#include <hip/hip_runtime.h>
#include <stdint.h>

#define TT 4096
#define HID 7168
#define QL 1536
#define NH 64
#define HD 128
#define QD 8192
#define KTOP 2048
#define WSCALE 0.011048543456039806f

typedef _Float16 f16;
typedef uint16_t u16;
typedef unsigned u32;
typedef __attribute__((ext_vector_type(4))) float f32x4;
typedef __attribute__((ext_vector_type(16))) float f32x16;
typedef __attribute__((ext_vector_type(8))) _Float16 f16x8;
typedef __attribute__((ext_vector_type(4))) _Float16 f16x4;

__device__ __forceinline__ void lds_load16(const void* g, void* l) {
  __builtin_amdgcn_global_load_lds(
      (const __attribute__((address_space(1))) unsigned*)g,
      (__attribute__((address_space(3))) unsigned*)l, 16, 0, 0);
}

__device__ __forceinline__ u16 f16_bits(f16 h) {
  union { f16 h; u16 u; } c; c.h = h; return c.u;
}
__device__ __forceinline__ float f16_from_bits(u16 u) {
  union { u16 u; f16 h; } c; c.u = u; return (float)c.h;
}

// ---------------- tiled transpose f32[R][C] -> f16 out[(c+orow0)][r] ----------------
__global__ void tcvt(const float* __restrict__ in, f16* __restrict__ out,
                     int R, int C, int ostride, int orow0) {
  __shared__ float tile[32][33];
  int cb = blockIdx.x * 32, rb = blockIdx.y * 32;
  int tx = threadIdx.x & 31, ty = threadIdx.x >> 5;  // ty 0..7
  for (int i = 0; i < 32; i += 8)
    tile[ty + i][tx] = in[(size_t)(rb + ty + i) * C + cb + tx];
  __syncthreads();
  for (int i = 0; i < 32; i += 8)
    out[(size_t)(cb + ty + i + orow0) * ostride + rb + tx] = (f16)tile[tx][ty + i];
}

// ---------------- q16 = f16(qr @ Wq_b)  (A fp32 via ds_write staging, B f16; 128x128, BK=32) ----------------
__launch_bounds__(256, 2)
__global__ void gemm_q(const float* __restrict__ A, const f16* __restrict__ B, f16* __restrict__ C) {
  __shared__ __align__(16) f16 As[128 * 32];
  __shared__ __align__(16) f16 Bs[128 * 32];
  int tid = threadIdx.x, lane = tid & 63, wave = tid >> 6;
  int bm = blockIdx.y << 7, bn = blockIdx.x << 7;
  int wm = (wave & 1) << 6, wn = (wave >> 1) << 6;
  const f16* gb = B + (size_t)(bn + (tid >> 2)) * QL + (tid & 3) * 8;
  f16* lB = Bs + wave * 512;
  int ar = tid >> 3, ac = (tid & 7) * 4;
  f32x4 acc[4][4] = {};
  for (int k0 = 0; k0 < QL; k0 += 32) {
    __syncthreads();
#pragma unroll
    for (int i = 0; i < 4; i++) {
      float4 v = *(const float4*)(A + (size_t)(bm + ar + i * 32) * QL + k0 + ac);
      f16x4 h = {(f16)v.x, (f16)v.y, (f16)v.z, (f16)v.w};
      *(f16x4*)(As + (ar + i * 32) * 32 + ac) = h;
    }
    lds_load16(gb + k0, lB);
    lds_load16(gb + (size_t)64 * QL + k0, lB + 2048);
    __syncthreads();
    int ro = lane & 15, ko = (lane >> 4) << 3;
    f16x8 af[4], bf[4];
#pragma unroll
    for (int i = 0; i < 4; i++) af[i] = *(const f16x8*)(As + (wm + i * 16 + ro) * 32 + ko);
#pragma unroll
    for (int i = 0; i < 4; i++) bf[i] = *(const f16x8*)(Bs + (wn + i * 16 + ro) * 32 + ko);
#pragma unroll
    for (int mi = 0; mi < 4; mi++)
#pragma unroll
      for (int ni = 0; ni < 4; ni++)
        acc[mi][ni] = __builtin_amdgcn_mfma_f32_16x16x32_f16(af[mi], bf[ni], acc[mi][ni], 0, 0, 0);
  }
  int cr = (lane >> 4) << 2, cc = lane & 15;
#pragma unroll
  for (int mi = 0; mi < 4; mi++)
#pragma unroll
    for (int ni = 0; ni < 4; ni++) {
      int row = bm + wm + mi * 16 + cr;
      int col = bn + wn + ni * 16 + cc;
      f16* cp = C + (size_t)row * QD + col;
#pragma unroll
      for (int r = 0; r < 4; r++) cp[(size_t)r * QD] = (f16)acc[mi][ni][r];
    }
}

// ---------------- [kraw | w] = hs @ [Wk | Wproj]  (A fp32 via ds_write staging; 64x64, BK=64) ----------------
__launch_bounds__(256, 2)
__global__ void gemm_kw(const float* __restrict__ A, const f16* __restrict__ B,
                        float* __restrict__ kraw, float* __restrict__ wout) {
  __shared__ __align__(16) f16 As[64 * 64];
  __shared__ __align__(16) f16 Bs[64 * 64];
  int tid = threadIdx.x, lane = tid & 63, wave = tid >> 6;
  int bm = blockIdx.y << 6, bn = blockIdx.x << 6;
  int wm = (wave & 1) << 5, wn = (wave >> 1) << 5;
  const f16* gb = B + (size_t)(bn + (tid >> 3)) * HID + (tid & 7) * 8;
  f16* lB = Bs + wave * 512;
  int ar = tid >> 4, ac = (tid & 15) * 4;
  f32x4 acc[2][2] = {};
  for (int k0 = 0; k0 < HID; k0 += 64) {
    __syncthreads();
#pragma unroll
    for (int i = 0; i < 4; i++) {
      float4 v = *(const float4*)(A + (size_t)(bm + ar + i * 16) * HID + k0 + ac);
      f16x4 h = {(f16)v.x, (f16)v.y, (f16)v.z, (f16)v.w};
      *(f16x4*)(As + (ar + i * 16) * 64 + ac) = h;
    }
    lds_load16(gb + k0, lB);
    lds_load16(gb + (size_t)32 * HID + k0, lB + 2048);
    __syncthreads();
    int ro = lane & 15, ko = (lane >> 4) << 3;
    f16x8 af[2][2], bf[2][2];
#pragma unroll
    for (int i = 0; i < 2; i++)
#pragma unroll
      for (int kk = 0; kk < 2; kk++) {
        af[i][kk] = *(const f16x8*)(As + (wm + i * 16 + ro) * 64 + kk * 32 + ko);
        bf[i][kk] = *(const f16x8*)(Bs + (wn + i * 16 + ro) * 64 + kk * 32 + ko);
      }
#pragma unroll
    for (int mi = 0; mi < 2; mi++)
#pragma unroll
      for (int ni = 0; ni < 2; ni++)
#pragma unroll
        for (int kk = 0; kk < 2; kk++)
          acc[mi][ni] = __builtin_amdgcn_mfma_f32_16x16x32_f16(af[mi][kk], bf[ni][kk], acc[mi][ni], 0, 0, 0);
  }
  int cr = (lane >> 4) << 2, cc = lane & 15;
#pragma unroll
  for (int mi = 0; mi < 2; mi++)
#pragma unroll
    for (int ni = 0; ni < 2; ni++) {
      int row = bm + wm + mi * 16 + cr;
      int col = bn + wn + ni * 16 + cc;
#pragma unroll
      for (int r = 0; r < 4; r++) {
        float v = acc[mi][ni][r];
        int rr = row + r;
        if (col < HD) kraw[(size_t)rr * HD + col] = v;
        else          wout[(size_t)rr * NH + (col - HD)] = v * WSCALE;
      }
    }
}

// ---------------- layernorm + rope on k -> f16 ----------------
__global__ void ln_rope(const float* __restrict__ kraw, const int* __restrict__ pos,
                        const float* __restrict__ gamma, const float* __restrict__ beta,
                        f16* __restrict__ k16) {
  int row = (blockIdx.x << 2) + (threadIdx.x >> 6);
  int lane = threadIdx.x & 63;
  const float* kr = kraw + (size_t)row * HD;
  float2 x = ((const float2*)kr)[lane];
  float s = x.x + x.y, s2 = x.x * x.x + x.y * x.y;
  for (int off = 32; off; off >>= 1) { s += __shfl_down(s, off); s2 += __shfl_down(s2, off); }
  s = __shfl(s, 0); s2 = __shfl(s2, 0);
  float mu = s * (1.f / 128.f);
  float var = s2 * (1.f / 128.f) - mu * mu;
  float inv = rsqrtf(var + 1e-6f);
  float y0 = (x.x - mu) * inv * gamma[lane * 2] + beta[lane * 2];
  float y1 = (x.y - mu) * inv * gamma[lane * 2 + 1] + beta[lane * 2 + 1];
  float o0 = y0, o1 = y1;
  if (lane < 32) {
    float p = (float)pos[row];
    float invf = exp2f(-(float)lane * 0.41524101185942813f);  // 10000^(-2l/64)
    float ang = p * invf;
    float sn, cn;
    sincosf(ang, &sn, &cn);
    o0 = y0 * cn - y1 * sn;
    o1 = y0 * sn + y1 * cn;
  }
  k16[(size_t)row * HD + 2 * lane] = (f16)o0;
  k16[(size_t)row * HD + 2 * lane + 1] = (f16)o1;
}

// ---------------- register-resident bitonic sort (ascending on ~key) + store ----------------
template <int N>
__device__ __forceinline__ void sort_and_store(u32* key, int tid, int t, float* out) {
  constexpr int V = N / 256;  // 8 or 16 keys per thread
  u32 v[V];
#pragma unroll
  for (int r = 0; r < V; r += 4) {
    uint4 q4 = *(const uint4*)(key + tid * V + r);
    v[r] = ~q4.x; v[r + 1] = ~q4.y; v[r + 2] = ~q4.z; v[r + 3] = ~q4.w;
  }
#pragma unroll
  for (int k = 2; k <= N; k <<= 1) {
#pragma unroll
    for (int j = k >> 1; j > 0; j >>= 1) {
      if (j >= 64 * V) {
        // cross-wave pass via LDS
#pragma unroll
        for (int r = 0; r < V; r += 4) {
          uint4 q4 = {v[r], v[r + 1], v[r + 2], v[r + 3]};
          *(uint4*)(key + tid * V + r) = q4;
        }
        __syncthreads();
        for (int m = tid; m < N / 2; m += 256) {
          int i = ((m & ~(j - 1)) << 1) | (m & (j - 1));
          int l = i | j;
          bool up = ((i & k) == 0);
          u32 a = key[i], b = key[l];
          if (up ? (a > b) : (a < b)) { key[i] = b; key[l] = a; }
        }
        __syncthreads();
#pragma unroll
        for (int r = 0; r < V; r += 4) {
          uint4 q4 = *(const uint4*)(key + tid * V + r);
          v[r] = q4.x; v[r + 1] = q4.y; v[r + 2] = q4.z; v[r + 3] = q4.w;
        }
      } else if (j >= V) {
        // cross-lane pass via shuffle
        int lanej = j / V;
        bool takeMin = (((tid & lanej) == 0) == (((tid * V) & k) == 0));
#pragma unroll
        for (int r = 0; r < V; r++) {
          u32 o = __shfl_xor(v[r], lanej, 64);
          u32 mn = min(v[r], o), mx = max(v[r], o);
          v[r] = takeMin ? mn : mx;
        }
      } else {
        // intra-thread pass: pure VALU
#pragma unroll
        for (int r = 0; r < V; r++) {
          if ((r & j) == 0) {
            bool up = (((tid * V + r) & k) == 0);
            u32 a = v[r], b = v[r | j];
            u32 mn = min(a, b), mx = max(a, b);
            v[r] = up ? mn : mx;
            v[r | j] = up ? mx : mn;
          }
        }
      }
    }
  }
  // elements 0..KTOP-1 (ascending ~key = descending key) -> output
  if (tid * V < KTOP) {
    float* ov = out + (size_t)t * KTOP + tid * V;
    float* oi = out + (size_t)TT * KTOP + (size_t)t * KTOP + tid * V;
#pragma unroll
    for (int r = 0; r < V; r++) {
      u32 kv = ~v[r];
      u32 mono = kv >> 16;
      float val;
      if (mono == 0u) {
        val = -1e30f;
      } else {
        u16 hb = (u16)((mono & 0x8000u) ? (mono ^ 0x8000u) : (mono ^ 0xFFFFu));
        val = f16_from_bits(hb);
      }
      ov[r] = val;
      oi[r] = (float)(0xFFFFu - (kv & 0xFFFFu));
    }
  }
}

// ---------------- per-row: rope(q), f16 MFMA scores (Q in regs), register bitonic top-k ----------------
__launch_bounds__(256, 3)
__global__ void scores_topk(const f16* __restrict__ q16, const f16* __restrict__ k16,
                            const float* __restrict__ w, const int* __restrict__ pos,
                            float* __restrict__ out) {
  int t = blockIdx.x;
  int tid = threadIdx.x, lane = tid & 63, wave = tid >> 6;
  __shared__ __align__(16) unsigned char smem[49408];
  f16* ks = (f16*)smem;                 // 32KB: K tile, units [kg(16)][s(128)] x 8 f16
  f16* qk = (f16*)(smem + 32768);       // 16KB: q row units; later 4096-key sort arena
  u32* key = (u32*)(smem + 32768);      // aliases qk
  float* css = (float*)(smem + 49152);  // 64 floats: cos[32] sin[32]

  // stage q row (contiguous global, permuted into [kg][h] units); build cos/sin
  {
    const f16* qrow = q16 + (size_t)t * QD;
#pragma unroll
    for (int j = 0; j < 4; j++) {
      int u = j * 256 + tid;
      int kg = u >> 6, h = u & 63;
      lds_load16(qrow + h * 128 + kg * 8, qk + (size_t)(j * 256 + wave * 64) * 8);
    }
    if (tid < 32) {
      float invf = exp2f(-(float)tid * 0.41524101185942813f);
      float ang = (float)pos[t] * invf;
      float sn, cn;
      sincosf(ang, &sn, &cn);
      css[tid] = cn;
      css[32 + tid] = sn;
    }
  }
  __syncthreads();
  // rope q in LDS: 64 heads x 32 pairs (dims 0..63)
#pragma unroll
  for (int i = 0; i < 8; i++) {
    int p = tid + (i << 8);
    int h = p >> 5, l = p & 31;
    int d = l * 2;
    int base = ((d >> 3) * 64 + h) * 8 + (d & 7);
    float q0 = (float)qk[base], q1 = (float)qk[base + 1];
    float cn = css[l], sn = css[32 + l];
    qk[base] = (f16)(q0 * cn - q1 * sn);
    qk[base + 1] = (f16)(q0 * sn + q1 * cn);
  }
  __syncthreads();
  // Q into registers: A-frags for 32x32x16 (m=lane&31, k=(lane>>5)*8+j)
  f16x8 afr[2][8];
  {
    int m = lane & 31;
#pragma unroll
    for (int mi = 0; mi < 2; mi++)
#pragma unroll
      for (int kk = 0; kk < 8; kk++) {
        int kg = kk * 2 + (lane >> 5);
        afr[mi][kk] = *(const f16x8*)(qk + (size_t)(kg * 64 + mi * 32 + m) * 8);
      }
  }
  // per-lane head weights (C-layout rows this lane owns)
  float wreg[32];
  {
    int hf = lane >> 5;
    const float* wr = w + (size_t)t * 64;
#pragma unroll
    for (int mi = 0; mi < 2; mi++)
#pragma unroll
      for (int r = 0; r < 16; r++)
        wreg[mi * 16 + r] = wr[mi * 32 + (r & 3) + ((r >> 2) << 3) + (hf << 2)];
  }
  __syncthreads();  // q reads done -> qk region becomes key[]

  int nsort = (t <= 2047) ? 2048 : 4096;
  for (int s = tid; s < nsort; s += 256)
    key[s] = 0xFFFFu - (u32)s;   // fill: mono16 = 0 sorts below all reals

  int ntile = (t >> 7) + 1;
  int sw = wave << 5;
  for (int st = 0; st < ntile; st++) {
    int s0 = st << 7;
    __syncthreads();
    {
      const f16* kb = k16 + (size_t)s0 * HD;
#pragma unroll
      for (int j = 0; j < 8; j++) {
        int u = j * 256 + tid;
        int kg = u >> 7, s = u & 127;
        lds_load16(kb + s * HD + kg * 8, ks + (size_t)(j * 256 + wave * 64) * 8);
      }
    }
    __syncthreads();
    f32x16 acc0 = {}, acc1 = {};
    int nlo = lane & 31;
#pragma unroll
    for (int kk = 0; kk < 8; kk++) {
      int kg = kk * 2 + (lane >> 5);
      f16x8 bfr = *(const f16x8*)(ks + (size_t)(kg * 128 + sw + nlo) * 8);
      acc0 = __builtin_amdgcn_mfma_f32_32x32x16_f16(afr[0][kk], bfr, acc0, 0, 0, 0);
      acc1 = __builtin_amdgcn_mfma_f32_32x32x16_f16(afr[1][kk], bfr, acc1, 0, 0, 0);
    }
    float partial = 0.f;
#pragma unroll
    for (int r = 0; r < 16; r++) {
      partial += wreg[r] * fmaxf(acc0[r], 0.f);
      partial += wreg[16 + r] * fmaxf(acc1[r], 0.f);
    }
    partial += __shfl_xor(partial, 32);
    int s = s0 + sw + nlo;
    if (lane < 32 && s <= t) {
      if (!(partial == partial)) partial = 0.f;                 // NaN scrub
      partial = fminf(fmaxf(partial, -60000.f), 60000.f);       // keep f16-finite
      u16 hb = f16_bits((f16)partial);
      u32 m = (hb & 0x8000u) ? (u32)(hb ^ 0xFFFFu) : (u32)(hb | 0x8000u);
      key[s] = (m << 16) | (0xFFFFu - (u32)s);
    }
  }
  __syncthreads();  // all keys visible

  if (t <= 2047) sort_and_store<2048>(key, tid, t, out);
  else           sort_and_store<4096>(key, tid, t, out);
}

extern "C" void kernel_launch(void* const* d_in, const int* in_sizes, int n_in,
                              void* d_out, int out_size, void* d_ws, size_t ws_size,
                              hipStream_t stream) {
  const float* hs = (const float*)d_in[0];
  const float* qr = (const float*)d_in[1];
  const int* pos = (const int*)d_in[2];
  const float* Wq = (const float*)d_in[3];
  const float* Wk = (const float*)d_in[4];
  const float* Wp = (const float*)d_in[5];
  const float* gamma = (const float*)d_in[6];
  const float* beta = (const float*)d_in[7];
  char* ws = (char*)d_ws;
  // small buffers first, big streams last; total 99,221,504 B
  float* kraw = (float*)ws;                 //  2,097,152
  float* wsc = (float*)(ws + 2097152);      //  1,048,576
  f16* k16 = (f16*)(ws + 3145728);          //  1,048,576
  f16* kwT = (f16*)(ws + 4194304);          //  2,752,512  f16 [192][7168]
  f16* wqT = (f16*)(ws + 6946816);          // 25,165,824  f16 [8192][1536]
  f16* q16 = (f16*)(ws + 32112640);         // 67,108,864  f16 [4096][8192]

  tcvt<<<dim3(256, 48), dim3(256), 0, stream>>>(Wq, wqT, QL, QD, QL, 0);
  tcvt<<<dim3(4, 224), dim3(256), 0, stream>>>(Wk, kwT, HID, HD, HID, 0);
  tcvt<<<dim3(2, 224), dim3(256), 0, stream>>>(Wp, kwT, HID, NH, HID, HD);
  gemm_kw<<<dim3(3, 64), dim3(256), 0, stream>>>(hs, kwT, kraw, wsc);
  ln_rope<<<dim3(1024), dim3(256), 0, stream>>>(kraw, pos, gamma, beta, k16);
  gemm_q<<<dim3(64, 32), dim3(256), 0, stream>>>(qr, wqT, q16);
  scores_topk<<<dim3(4096), dim3(256), 0, stream>>>(q16, k16, wsc, pos, (float*)d_out);
}